// Round 20
// baseline (760.321 us; speedup 1.0000x reference)
//
#include <hip/hip_runtime.h>
#include <hip/hip_cooperative_groups.h>
#include <cstdint>
#include <cstddef>

namespace cg = cooperative_groups;

#define DI __device__ __forceinline__

typedef int v4i  __attribute__((ext_vector_type(4)));
typedef int v16i __attribute__((ext_vector_type(16)));

#if defined(__has_builtin)
#if __has_builtin(__builtin_amdgcn_sdot4)
#define HAS_SDOT4 1
#endif
#if __has_builtin(__builtin_amdgcn_alignbyte)
#define HAS_ALIGNBYTE 1
#endif
#endif

DI int dot4(unsigned a, unsigned b, int c) {
#ifdef HAS_SDOT4
  return __builtin_amdgcn_sdot4((int)a, (int)b, c, false);
#else
#pragma unroll
  for (int k = 0; k < 4; ++k)
    c += (int)(signed char)(a >> (8 * k)) * (int)(signed char)(b >> (8 * k));
  return c;
#endif
}

DI unsigned alignb(unsigned hi, unsigned lo, int sh) {
#ifdef HAS_ALIGNBYTE
  return __builtin_amdgcn_alignbyte(hi, lo, sh);
#else
  return sh ? ((lo >> (8 * sh)) | (hi << (32 - 8 * sh))) : lo;
#endif
}

DI float qclamp(int a, float h) {  // clamp(rint(a*h), 0, 15) as float
  return fminf(fmaxf(rintf((float)a * h), 0.f), 15.f);
}

// ---------------- scalar block in workspace ----------------
struct Scal {
  unsigned max_x, max_w1, max_w2, max_wf1, max_wf2;
  int max1, max2;
};

DI float mkscale(unsigned bits, float d) { return fmaxf(__uint_as_float(bits), 1e-8f) / d; }
DI float d_s_in(const Scal* sc) { return mkscale(sc->max_x, 7.f); }
DI float d_sw1(const Scal* sc)  { return mkscale(sc->max_w1, 7.f); }
DI float d_sw2(const Scal* sc)  { return mkscale(sc->max_w2, 7.f); }
DI float d_s1(const Scal* sc)   { return fmaxf((float)sc->max1 * (d_s_in(sc) * d_sw1(sc)), 1e-8f) / 15.f; }
DI float d_s2(const Scal* sc)   { return fmaxf((float)sc->max2 * (d_s1(sc) * d_sw2(sc)), 1e-8f) / 15.f; }

static constexpr int NX   = 32 * 3 * 224 * 224;
static constexpr int NP1  = 32 * 32 * 222 * 224;
static constexpr int NQX  = NX / 4 / 256;           // 4704
static constexpr int NT2  = 6160;                   // conv2 tile-blocks

// ---------------- reduction helpers (blockDim == 256) ----------------
DI float wave_maxf(float v) { for (int o = 32; o; o >>= 1) v = fmaxf(v, __shfl_down(v, o, 64)); return v; }
DI int   wave_maxi(int v)   { for (int o = 32; o; o >>= 1) v = max(v, __shfl_down(v, o, 64));   return v; }

DI float block_maxf(float v) {
  __shared__ float s[4];
  v = wave_maxf(v);
  int lane = threadIdx.x & 63, w = threadIdx.x >> 6;
  if (!lane) s[w] = v;
  __syncthreads();
  if (threadIdx.x < 64) {
    float t = (threadIdx.x < 4) ? s[threadIdx.x] : 0.f;
    v = wave_maxf(t);
  }
  return v;
}

DI int block_maxi(int v) {
  __shared__ int s[4];
  v = wave_maxi(v);
  int lane = threadIdx.x & 63, w = threadIdx.x >> 6;
  if (!lane) s[w] = v;
  __syncthreads();
  if (threadIdx.x < 64) {
    int t = (threadIdx.x < 4) ? s[threadIdx.x] : 0;
    v = wave_maxi(t);
  }
  return v;
}

// ================= fused cooperative kernel =================
__global__ void __launch_bounds__(256, 4) k_all(
    const float4* __restrict__ x,
    const float* __restrict__ w1, const float* __restrict__ b1,
    const float* __restrict__ w2, const float* __restrict__ b2,
    const float* __restrict__ wf1, const float* __restrict__ bf1,
    const float* __restrict__ wf2, const float* __restrict__ bf2,
    Scal* sc, unsigned* __restrict__ xq, unsigned* __restrict__ w1pk,
    unsigned* __restrict__ w2frag, int* __restrict__ bint1,
    unsigned char* __restrict__ y1n, int* __restrict__ pooled_i,
    float* __restrict__ gwq, float* __restrict__ out) {
  cg::grid_group grid = cg::this_grid();
  __shared__ __align__(16) char sm[27648];
  int tid = threadIdx.x;
  int bid = blockIdx.x;
  int G = gridDim.x;

  // ---- stage Z: zero scalars + pooled ----
  if (bid == 0) {
    for (int i = tid; i < 2048; i += 256) pooled_i[i] = 0;
    if (tid < 16) ((unsigned*)sc)[tid] = 0;
  }
  grid.sync();

  // ---- stage A: absmax ----
  for (int vb = bid; vb < 1028; vb += G) {
    __syncthreads();
    if (vb < 1024) {
      float m = 0.f;
      for (int i = vb * 256 + tid; i < NX / 4; i += 1024 * 256) {
        float4 v = x[i];
        m = fmaxf(m, fmaxf(fmaxf(fabsf(v.x), fabsf(v.y)), fmaxf(fabsf(v.z), fabsf(v.w))));
      }
      m = block_maxf(m);
      if (!tid) atomicMax(&sc->max_x, __float_as_uint(m));
    } else {
      const float* p; int n; unsigned* slot;
      int wb = vb - 1024;
      if (wb == 0)      { p = w1;  n = 864;   slot = &sc->max_w1; }
      else if (wb == 1) { p = w2;  n = 18432; slot = &sc->max_w2; }
      else if (wb == 2) { p = wf1; n = 8192;  slot = &sc->max_wf1; }
      else              { p = wf2; n = 1280;  slot = &sc->max_wf2; }
      float m = 0.f;
      for (int i = tid; i < n; i += 256) m = fmaxf(m, fabsf(p[i]));
      m = block_maxf(m);
      if (!tid) atomicMax(slot, __float_as_uint(m));
    }
  }
  grid.sync();

  // ---- stage B: quantize x + pack w1/w2/bias1 ----
  for (int vb = bid; vb < NQX + 22; vb += G) {
    if (vb < NQX) {
      float s = d_s_in(sc);
      int i = vb * 256 + tid;
      float4 v = x[i];
      float f[4] = {v.x, v.y, v.z, v.w};
      unsigned w = 0;
#pragma unroll
      for (int k = 0; k < 4; ++k) {
        float q = rintf(f[k] / s);
        q = fminf(fmaxf(q, -8.f), 7.f);
        w |= ((unsigned)((int)q & 255)) << (8 * k);
      }
      xq[i] = w;
    } else {
      int i = (vb - NQX) * 256 + tid;
      if (i < 288) {
        int oc = i / 9, r = i - oc * 9;
        float s = d_sw1(sc);
        unsigned w = 0;
#pragma unroll
        for (int k = 0; k < 3; ++k) {
          float q = rintf(w1[oc * 27 + r * 3 + k] / s);
          q = fminf(fmaxf(q, -8.f), 7.f);
          w |= ((unsigned)((int)q & 255)) << (8 * k);
        }
        w1pk[i] = w;
      } else if (i < 288 + 4608) {
        int j = i - 288;
        int icq = j & 7; int t = j >> 3;
        int kw = t % 3; t /= 3;
        int kh = t % 3; int oc = t / 3;
        float s = d_sw2(sc);
        unsigned w = 0;
#pragma unroll
        for (int k = 0; k < 4; ++k) {
          int ic = icq * 4 + k;
          float q = rintf(w2[(oc * 32 + ic) * 9 + kh * 3 + kw] / s);
          q = fminf(fmaxf(q, -8.f), 7.f);
          w |= ((unsigned)((int)q & 255)) << (8 * k);
        }
        int tap = kh * 3 + kw;
        int dl = (oc & 31) | ((icq >> 2) << 5);
        w2frag[(((tap * 2) + (oc >> 5)) * 64 + dl) * 4 + (icq & 3)] = w;
      } else if (i < 288 + 4608 + 32) {
        int j = i - 4896;
        bint1[j] = (int)rintf(b1[j] / (d_s_in(sc) * d_sw1(sc)));
      }
    }
  }
  grid.sync();

  // ---- conv1 shared views ----
  signed char* lx = (signed char*)sm;
  unsigned* lw1 = (unsigned*)(sm + 5408);
  int* lb1 = (int*)(sm + 6560);

  // ---- stage C: conv1 pass A (max only) ----
  {
    int mxall = 0;
    for (int vb = bid; vb < 37 * 32; vb += G) {
      __syncthreads();
      int strip = vb % 37, b = vb / 37;
      int oh0 = strip * 6;
      for (int i = tid; i < 288; i += 256) lw1[i] = w1pk[i];
      if (tid < 32) lb1[tid] = bint1[tid];
      {
        const unsigned* src = (const unsigned*)xq + (size_t)b * 3 * 224 * 56;
        unsigned* dst = (unsigned*)lx;
#pragma unroll
        for (int it = 0; it < 6; ++it) {
          int i = it * 256 + tid;
          if (i < 1344) {
            int row = i / 56, d = i - row * 56;
            int ic = row >> 3, r = row & 7;
            dst[i] = src[(ic * 224 + (oh0 + r)) * 56 + d];
          }
        }
      }
      __syncthreads();
      for (int it = 0; it < 21; ++it) {
        int i = it * 256 + tid;
        int g = i % 28;
        int r = i / 28;
        int oh_l = r % 6;
        int oc = r / 6;
        int bias = lb1[oc];
        int acc[8];
#pragma unroll
        for (int j = 0; j < 8; ++j) acc[j] = bias;
#pragma unroll
        for (int seg = 0; seg < 9; ++seg) {
          int ic = seg / 3, kh = seg - ic * 3;
          const signed char* base = lx + (ic * 8 + oh_l + kh) * 224 + g * 8;
          uint2 lo = *(const uint2*)base;
          unsigned d0 = lo.x, d1 = lo.y;
          unsigned d2 = *(const unsigned*)(base + 8);
          unsigned wr = lw1[oc * 9 + ic * 3 + kh];
          acc[0] = dot4(d0, wr, acc[0]);
          acc[1] = dot4(alignb(d1, d0, 1), wr, acc[1]);
          acc[2] = dot4(alignb(d1, d0, 2), wr, acc[2]);
          acc[3] = dot4(alignb(d1, d0, 3), wr, acc[3]);
          acc[4] = dot4(d1, wr, acc[4]);
          acc[5] = dot4(alignb(d2, d1, 1), wr, acc[5]);
          acc[6] = dot4(alignb(d2, d1, 2), wr, acc[6]);
          acc[7] = dot4(alignb(d2, d1, 3), wr, acc[7]);
        }
#pragma unroll
        for (int j = 0; j < 8; ++j) if (g * 8 + j < 222) mxall = max(mxall, acc[j]);
      }
    }
    __syncthreads();
    int m = block_maxi(max(mxall, 0));
    if (!tid) atomicMax(&sc->max1, m);
  }
  grid.sync();

  // ---- stage D: conv1 pass B (recompute + quantize + NHWC store) ----
  {
    float h1 = (d_s_in(sc) * d_sw1(sc)) / d_s1(sc);
    for (int vb = bid; vb < 37 * 32; vb += G) {
      __syncthreads();
      int strip = vb % 37, b = vb / 37;
      int oh0 = strip * 6;
      for (int i = tid; i < 288; i += 256) lw1[i] = w1pk[i];
      if (tid < 32) lb1[tid] = bint1[tid];
      {
        const unsigned* src = (const unsigned*)xq + (size_t)b * 3 * 224 * 56;
        unsigned* dst = (unsigned*)lx;
#pragma unroll
        for (int it = 0; it < 6; ++it) {
          int i = it * 256 + tid;
          if (i < 1344) {
            int row = i / 56, d = i - row * 56;
            int ic = row >> 3, r = row & 7;
            dst[i] = src[(ic * 224 + (oh0 + r)) * 56 + d];
          }
        }
      }
      __syncthreads();
      for (int it = 0; it < 21; ++it) {
        int t = it * 256 + tid;
        int oc4 = t & 7;
        int r2 = t >> 3;
        int g2 = r2 % 112;
        int oh_l = r2 / 112;
        int p = g2 * 2;
        int qb = p & ~3, sh = p & 3;
        int oc0 = oc4 * 4;
        int acc0[4], acc1[4];
#pragma unroll
        for (int c = 0; c < 4; ++c) { acc0[c] = lb1[oc0 + c]; acc1[c] = acc0[c]; }
#pragma unroll
        for (int seg = 0; seg < 9; ++seg) {
          int ic = seg / 3, kh = seg - ic * 3;
          const signed char* base = lx + (ic * 8 + oh_l + kh) * 224 + qb;
          unsigned d0 = *(const unsigned*)base;
          unsigned d1 = *(const unsigned*)(base + 4);
          unsigned wpx0 = alignb(d1, d0, sh);
          unsigned wpx1 = alignb(d1, d0, sh + 1);
#pragma unroll
          for (int c = 0; c < 4; ++c) {
            unsigned wr = lw1[(oc0 + c) * 9 + seg];
            acc0[c] = dot4(wpx0, wr, acc0[c]);
            acc1[c] = dot4(wpx1, wr, acc1[c]);
          }
        }
        unsigned cw0 = 0, cw1 = 0;
#pragma unroll
        for (int c = 0; c < 4; ++c) {
          cw0 |= ((unsigned)(int)qclamp(acc0[c], h1)) << (8 * c);
          cw1 |= ((unsigned)(int)qclamp(acc1[c], h1)) << (8 * c);
        }
        size_t pidx = (size_t)(b * 222 + oh0 + oh_l) * 224 + p;
        unsigned* dst = (unsigned*)(y1n + pidx * 32 + oc0);
        dst[0] = cw0;
        dst[8] = cw1;
      }
    }
  }
  grid.sync();

  // ---- conv2 shared views + balanced contiguous partition ----
  unsigned* lw2 = (unsigned*)sm;                   // 18432
  int* ls = (int*)(sm + 18432);                    // 8192
  int* lb2 = (int*)(sm + 26624);                   // 256
  int lane = tid & 63;
  int lane31 = lane & 31, lhalf = lane >> 5;
  size_t aoff = (size_t)lane31 * 32 + (size_t)lhalf * 16;
  int t0 = (int)(((long)NT2 * bid) / G);
  int t1 = (int)(((long)NT2 * (bid + 1)) / G);

  // ---- stage E: conv2 pass A (max only) ----
  {
    for (int i = tid; i < 4608; i += 256) lw2[i] = w2frag[i];
    if (tid < 64) {
      float sb = d_s1(sc) * d_sw2(sc);
      lb2[tid] = (int)rintf(b2[tid] / sb);
    }
    __syncthreads();
    int bias0 = lb2[lane31], bias1 = lb2[32 + lane31];
    int mx = 0;
    for (int tb = t0; tb < t1; ++tb) {
      int wv = tb * 4 + (tid >> 6);
      int owg = wv % 7; int t = wv / 7;
      int ohg = t % 110; int b = t / 110;
      int oh0 = ohg * 2, ow0 = owg * 32;
      const unsigned char* base0 = y1n + ((size_t)((b * 222 + oh0) * 224 + ow0)) * 32 + aoff;
      v4i a[4][3];
#pragma unroll
      for (int i = 0; i < 4; ++i)
#pragma unroll
        for (int kw = 0; kw < 3; ++kw)
          a[i][kw] = *(const v4i*)(base0 + (size_t)i * (224 * 32) + kw * 32);
      v16i acc00, acc01, acc10, acc11;
#pragma unroll
      for (int r = 0; r < 16; ++r) {
        acc00[r] = bias0; acc01[r] = bias1;
        acc10[r] = bias0; acc11[r] = bias1;
      }
#pragma unroll
      for (int kh = 0; kh < 3; ++kh)
#pragma unroll
        for (int kw = 0; kw < 3; ++kw) {
          int tap = kh * 3 + kw;
          v4i b0 = *(const v4i*)(lw2 + (tap * 2 + 0) * 256 + lane * 4);
          v4i b1 = *(const v4i*)(lw2 + (tap * 2 + 1) * 256 + lane * 4);
          acc00 = __builtin_amdgcn_mfma_i32_32x32x32_i8(a[kh][kw], b0, acc00, 0, 0, 0);
          acc01 = __builtin_amdgcn_mfma_i32_32x32x32_i8(a[kh][kw], b1, acc01, 0, 0, 0);
          acc10 = __builtin_amdgcn_mfma_i32_32x32x32_i8(a[kh + 1][kw], b0, acc10, 0, 0, 0);
          acc11 = __builtin_amdgcn_mfma_i32_32x32x32_i8(a[kh + 1][kw], b1, acc11, 0, 0, 0);
        }
      if (owg != 6) {
#pragma unroll
        for (int r = 0; r < 16; ++r)
          mx = max(mx, max(max(acc00[r], acc01[r]), max(acc10[r], acc11[r])));
      } else {
#pragma unroll
        for (int r = 0; r < 16; ++r) {
          int m = (r & 3) + 8 * (r >> 2) + 4 * lhalf;
          if (ow0 + m < 220)
            mx = max(mx, max(max(acc00[r], acc01[r]), max(acc10[r], acc11[r])));
        }
      }
    }
    __syncthreads();
    mx = block_maxi(max(mx, 0));
    if (!tid) atomicMax(&sc->max2, mx);
  }
  grid.sync();

  // ---- stage F: conv2 pass B (recompute + quantize + fused pool) ----
  {
    for (int i = tid; i < 2048; i += 256) ls[i] = 0;  // lw2/lb2 persist
    __syncthreads();
    int bias0 = lb2[lane31], bias1 = lb2[32 + lane31];
    float h = (d_s1(sc) * d_sw2(sc)) * (1.0f / d_s2(sc));
    for (int tb = t0; tb < t1; ++tb) {
      int wv = tb * 4 + (tid >> 6);
      int owg = wv % 7; int t = wv / 7;
      int ohg = t % 110; int b = t / 110;
      int oh0 = ohg * 2, ow0 = owg * 32;
      const unsigned char* base0 = y1n + ((size_t)((b * 222 + oh0) * 224 + ow0)) * 32 + aoff;
      v4i a[4][3];
#pragma unroll
      for (int i = 0; i < 4; ++i)
#pragma unroll
        for (int kw = 0; kw < 3; ++kw)
          a[i][kw] = *(const v4i*)(base0 + (size_t)i * (224 * 32) + kw * 32);
      v16i acc00, acc01, acc10, acc11;
#pragma unroll
      for (int r = 0; r < 16; ++r) {
        acc00[r] = bias0; acc01[r] = bias1;
        acc10[r] = bias0; acc11[r] = bias1;
      }
#pragma unroll
      for (int kh = 0; kh < 3; ++kh)
#pragma unroll
        for (int kw = 0; kw < 3; ++kw) {
          int tap = kh * 3 + kw;
          v4i b0 = *(const v4i*)(lw2 + (tap * 2 + 0) * 256 + lane * 4);
          v4i b1 = *(const v4i*)(lw2 + (tap * 2 + 1) * 256 + lane * 4);
          acc00 = __builtin_amdgcn_mfma_i32_32x32x32_i8(a[kh][kw], b0, acc00, 0, 0, 0);
          acc01 = __builtin_amdgcn_mfma_i32_32x32x32_i8(a[kh][kw], b1, acc01, 0, 0, 0);
          acc10 = __builtin_amdgcn_mfma_i32_32x32x32_i8(a[kh + 1][kw], b0, acc10, 0, 0, 0);
          acc11 = __builtin_amdgcn_mfma_i32_32x32x32_i8(a[kh + 1][kw], b1, acc11, 0, 0, 0);
        }
      float fs0 = 0.f, fs1 = 0.f;
      if (owg != 6) {
#pragma unroll
        for (int r = 0; r < 16; ++r) {
          fs0 += qclamp(acc00[r], h) + qclamp(acc10[r], h);
          fs1 += qclamp(acc01[r], h) + qclamp(acc11[r], h);
        }
      } else {
#pragma unroll
        for (int r = 0; r < 16; ++r) {
          int m = (r & 3) + 8 * (r >> 2) + 4 * lhalf;
          if (ow0 + m < 220) {
            fs0 += qclamp(acc00[r], h) + qclamp(acc10[r], h);
            fs1 += qclamp(acc01[r], h) + qclamp(acc11[r], h);
          }
        }
      }
      int isum0 = (int)fs0, isum1 = (int)fs1;
      isum0 += __shfl_down(isum0, 32, 64);
      isum1 += __shfl_down(isum1, 32, 64);
      if (lhalf == 0) {
        atomicAdd(&ls[b * 64 + lane31], isum0);
        atomicAdd(&ls[b * 64 + 32 + lane31], isum1);
      }
    }
    __syncthreads();
    for (int i = tid; i < 2048; i += 256) {
      int v = ls[i];
      if (v != 0) atomicAdd(&pooled_i[i], v);
    }
  }
  grid.sync();

  // ---- stage G: FC head + log_softmax (block 0 only) ----
  if (bid == 0) {
    float* pl = (float*)sm;
    float* y3 = (float*)(sm + 8192);
    float* zz = (float*)(sm + 24832);
    __shared__ float s3sh;
    float swf1 = mkscale(sc->max_wf1, 7.f), swf2 = mkscale(sc->max_wf2, 7.f);
    float s2 = d_s2(sc);
    for (int i = tid; i < 8192; i += 256) {
      float q = rintf(wf1[i] / swf1);
      q = fminf(fmaxf(q, -8.f), 7.f);
      gwq[i] = q * swf1;
    }
    for (int i = tid; i < 2048; i += 256) pl[i] = (float)pooled_i[i] * s2 / 48400.0f;
    __threadfence_block();
    __syncthreads();
    float sb1 = s2 * swf1;
    float lmax = 0.f;
    for (int o = tid; o < 4096; o += 256) {
      int b = o >> 7, j = o & 127;
      float acc = rintf(bf1[j] / sb1) * sb1;
      const float* wrow = &gwq[j * 64];
      const float* xrow = &pl[b * 64];
#pragma unroll 16
      for (int k = 0; k < 64; ++k) acc += xrow[k] * wrow[k];
      float r = fmaxf(acc, 0.f);
      y3[b * 130 + j] = r;
      lmax = fmaxf(lmax, r);
    }
    float m = block_maxf(lmax);
    if (!tid) s3sh = fmaxf(m, 1e-8f) / 15.f;
    __syncthreads();
    float s3 = s3sh;
    float sb2 = s3 * swf2;
    for (int o = tid; o < 320; o += 256) {
      int b = o / 10, j = o - b * 10;
      float acc = rintf(bf2[j] / sb2) * sb2;
      const float* yy = &y3[b * 130];
      const float* wrow = &wf2[j * 128];
#pragma unroll 16
      for (int k = 0; k < 128; ++k) {
        float q = rintf(yy[k] / s3);
        q = fminf(fmaxf(q, 0.f), 15.f);
        float wv = rintf(wrow[k] / swf2);
        wv = fminf(fmaxf(wv, -8.f), 7.f);
        acc += (q * s3) * (wv * swf2);
      }
      zz[o] = acc;
    }
    __syncthreads();
    if (tid < 32) {
      const float* z = &zz[tid * 10];
      float mm = z[0];
      for (int k = 1; k < 10; ++k) mm = fmaxf(mm, z[k]);
      float ssum = 0.f;
      for (int k = 0; k < 10; ++k) ssum += expf(z[k] - mm);
      float l = mm + logf(ssum);
      for (int k = 0; k < 10; ++k) out[tid * 10 + k] = z[k] - l;
    }
  }
}

extern "C" void kernel_launch(void* const* d_in, const int* in_sizes, int n_in,
                              void* d_out, int out_size, void* d_ws, size_t ws_size,
                              hipStream_t stream) {
  const float4* x  = (const float4*)d_in[0];
  const float* w1  = (const float*)d_in[1];
  const float* b1  = (const float*)d_in[2];
  const float* w2  = (const float*)d_in[3];
  const float* b2  = (const float*)d_in[4];
  const float* wf1 = (const float*)d_in[5];
  const float* bf1 = (const float*)d_in[6];
  const float* wf2 = (const float*)d_in[7];
  const float* bf2 = (const float*)d_in[8];
  float* out = (float*)d_out;

  char* ws = (char*)d_ws;
  Scal* sc = (Scal*)ws;
  int* pooled_i = (int*)(ws + 1024);
  size_t off = 1024 + 8192;
  unsigned* xq = (unsigned*)(ws + off);         off += (size_t)NX + 256;
  off = (off + 255) & ~(size_t)255;
  unsigned* w1pk = (unsigned*)(ws + off);       off += 2048;
  unsigned* w2frag = (unsigned*)(ws + off);     off += 4608 * 4;
  int* bint1 = (int*)(ws + off);                off += 256;
  float* gwq = (float*)(ws + off);              off += 8192 * 4;
  unsigned char* y1n = (unsigned char*)(ws + off); off += (size_t)NP1 + 256;
  (void)ws_size; (void)in_sizes; (void)n_in; (void)out_size;

  // occupancy-adaptive cooperative grid (pure host query, capture-safe)
  int nb = 0;
  hipOccupancyMaxActiveBlocksPerMultiprocessor(&nb, (const void*)k_all, 256, 0);
  if (nb < 1) nb = 1;
  int grid = nb * 256;            // 256 CUs on MI355X
  if (grid > 1024) grid = 1024;

  void* args[] = {
    (void*)&x, (void*)&w1, (void*)&b1, (void*)&w2, (void*)&b2,
    (void*)&wf1, (void*)&bf1, (void*)&wf2, (void*)&bf2,
    (void*)&sc, (void*)&xq, (void*)&w1pk, (void*)&w2frag, (void*)&bint1,
    (void*)&y1n, (void*)&pooled_i, (void*)&gwq, (void*)&out
  };
  hipLaunchCooperativeKernel((const void*)k_all, dim3(grid), dim3(256),
                             args, 0, stream);
}

// Round 22
// 289.227 us; speedup vs baseline: 2.6288x; 2.6288x over previous
//
#include <hip/hip_runtime.h>
#include <cstdint>
#include <cstddef>

#define DI __device__ __forceinline__

typedef int v4i  __attribute__((ext_vector_type(4)));
typedef int v16i __attribute__((ext_vector_type(16)));

#if defined(__has_builtin)
#if __has_builtin(__builtin_amdgcn_sdot4)
#define HAS_SDOT4 1
#endif
#if __has_builtin(__builtin_amdgcn_alignbyte)
#define HAS_ALIGNBYTE 1
#endif
#endif

DI int dot4(unsigned a, unsigned b, int c) {
#ifdef HAS_SDOT4
  return __builtin_amdgcn_sdot4((int)a, (int)b, c, false);
#else
#pragma unroll
  for (int k = 0; k < 4; ++k)
    c += (int)(signed char)(a >> (8 * k)) * (int)(signed char)(b >> (8 * k));
  return c;
#endif
}

DI unsigned alignb(unsigned hi, unsigned lo, int sh) {  // bytes (hi:lo) >> 8*sh
#ifdef HAS_ALIGNBYTE
  return __builtin_amdgcn_alignbyte(hi, lo, sh);
#else
  return sh ? ((lo >> (8 * sh)) | (hi << (32 - 8 * sh))) : lo;
#endif
}

DI float qclamp(int a, float h) {  // clamp(rint(a*h), 0, 15) as float
  return fminf(fmaxf(rintf((float)a * h), 0.f), 15.f);
}

DI unsigned pack4(float4 v, float s) {  // quantize 4 floats -> 4 int8 codes
  float f[4] = {v.x, v.y, v.z, v.w};
  unsigned w = 0;
#pragma unroll
  for (int k = 0; k < 4; ++k) {
    float q = rintf(f[k] / s);
    q = fminf(fmaxf(q, -8.f), 7.f);
    w |= ((unsigned)((int)q & 255)) << (8 * k);
  }
  return w;
}

// ---------------- scalar block in workspace ----------------
struct Scal {
  unsigned max_x, max_w1, max_w2, max_wf1, max_wf2;  // float bits (abs-max, >=0)
  int max1, max2;
};

DI float mkscale(unsigned bits, float d) { return fmaxf(__uint_as_float(bits), 1e-8f) / d; }
DI float d_s_in(const Scal* sc) { return mkscale(sc->max_x, 7.f); }
DI float d_sw1(const Scal* sc)  { return mkscale(sc->max_w1, 7.f); }
DI float d_sw2(const Scal* sc)  { return mkscale(sc->max_w2, 7.f); }
DI float d_s1(const Scal* sc)   { return fmaxf((float)sc->max1 * (d_s_in(sc) * d_sw1(sc)), 1e-8f) / 15.f; }
DI float d_s2(const Scal* sc)   { return fmaxf((float)sc->max2 * (d_s1(sc) * d_sw2(sc)), 1e-8f) / 15.f; }

static constexpr int NX   = 32 * 3 * 224 * 224;     // 4,816,896
static constexpr int NP1  = 32 * 32 * 222 * 224;    // y1n bytes (padded NHWC codes)
static constexpr int NBLK2 = 1540;                  // conv2 blocks (6.01/CU)
static constexpr int ITER2 = 4;                     // contiguous tiles per wave (6160 total)

// ---------------- reduction helpers (blockDim == 256) ----------------
DI float wave_maxf(float v) { for (int o = 32; o; o >>= 1) v = fmaxf(v, __shfl_down(v, o, 64)); return v; }
DI int   wave_maxi(int v)   { for (int o = 32; o; o >>= 1) v = max(v, __shfl_down(v, o, 64));   return v; }

DI float block_maxf(float v) {
  __shared__ float s[4];
  v = wave_maxf(v);
  int lane = threadIdx.x & 63, w = threadIdx.x >> 6;
  if (!lane) s[w] = v;
  __syncthreads();
  if (threadIdx.x < 64) {
    float t = (threadIdx.x < 4) ? s[threadIdx.x] : 0.f;
    v = wave_maxf(t);
  }
  return v;
}

DI int block_maxi(int v) {
  __shared__ int s[4];
  v = wave_maxi(v);
  int lane = threadIdx.x & 63, w = threadIdx.x >> 6;
  if (!lane) s[w] = v;
  __syncthreads();
  if (threadIdx.x < 64) {
    int t = (threadIdx.x < 4) ? s[threadIdx.x] : 0;
    v = wave_maxi(t);
  }
  return v;
}

// ---------------- stage kernels ----------------
// merged absmax: blocks 0..1023 = x (grid-stride); 1024..1027 = weights
__global__ void k_absmax_xw(const float4* __restrict__ x, int n4,
                            const float* __restrict__ w1, const float* __restrict__ w2,
                            const float* __restrict__ wf1, const float* __restrict__ wf2,
                            Scal* sc) {
  if (blockIdx.x < 1024) {
    float m = 0.f;
    for (int i = blockIdx.x * 256 + threadIdx.x; i < n4; i += 1024 * 256) {
      float4 v = x[i];
      m = fmaxf(m, fmaxf(fmaxf(fabsf(v.x), fabsf(v.y)), fmaxf(fabsf(v.z), fabsf(v.w))));
    }
    m = block_maxf(m);
    if (!threadIdx.x) atomicMax(&sc->max_x, __float_as_uint(m));
    return;
  }
  const float* p; int n; unsigned* slot;
  int wb = blockIdx.x - 1024;
  if (wb == 0)      { p = w1;  n = 864;   slot = &sc->max_w1; }
  else if (wb == 1) { p = w2;  n = 18432; slot = &sc->max_w2; }
  else if (wb == 2) { p = wf1; n = 8192;  slot = &sc->max_wf1; }
  else              { p = wf2; n = 1280;  slot = &sc->max_wf2; }
  float m = 0.f;
  for (int i = threadIdx.x; i < n; i += 256) m = fmaxf(m, fabsf(p[i]));
  m = block_maxf(m);
  if (!threadIdx.x) atomicMax(slot, __float_as_uint(m));
}

// conv1 pass A: quantize-while-staging (x floats -> LDS codes), per-block
// w1/bias packing from raw inputs, MAX ONLY. Blocks >= 1184 pack w2frag.
__global__ void __launch_bounds__(256) k_conv1a(
    const float4* __restrict__ x, const float* __restrict__ w1,
    const float* __restrict__ b1, const float* __restrict__ w2,
    const Scal* __restrict__ sc, unsigned* __restrict__ w2frag,
    int* __restrict__ max1) {
  int tid = threadIdx.x;
  if (blockIdx.x >= 1184) {   // 18 blocks: pack w2 into MFMA B-frag layout
    int j = (blockIdx.x - 1184) * 256 + tid;   // 0..4607
    int icq = j & 7; int t = j >> 3;
    int kw = t % 3; t /= 3;
    int kh = t % 3; int oc = t / 3;
    float s = d_sw2(sc);
    unsigned w = 0;
#pragma unroll
    for (int k = 0; k < 4; ++k) {
      int ic = icq * 4 + k;
      float q = rintf(w2[(oc * 32 + ic) * 9 + kh * 3 + kw] / s);
      q = fminf(fmaxf(q, -8.f), 7.f);
      w |= ((unsigned)((int)q & 255)) << (8 * k);
    }
    int tap = kh * 3 + kw;
    int dl = (oc & 31) | ((icq >> 2) << 5);
    w2frag[(((tap * 2) + (oc >> 5)) * 64 + dl) * 4 + (icq & 3)] = w;
    return;
  }

  __shared__ signed char lx[3 * 8 * 224 + 16];
  __shared__ unsigned lw[288];
  __shared__ int lb[32];
  int strip = blockIdx.x % 37;   // 0..36
  int b = blockIdx.x / 37;       // 0..31
  int oh0 = strip * 6;
  float s_in = d_s_in(sc), sw1 = d_sw1(sc);

  for (int i = tid; i < 288; i += 256) {
    int oc = i / 9, r = i - oc * 9;
    unsigned w = 0;
#pragma unroll
    for (int k = 0; k < 3; ++k) {
      float q = rintf(w1[oc * 27 + r * 3 + k] / sw1);
      q = fminf(fmaxf(q, -8.f), 7.f);
      w |= ((unsigned)((int)q & 255)) << (8 * k);
    }
    lw[i] = w;
  }
  if (tid < 32) lb[tid] = (int)rintf(b1[tid] / (s_in * sw1));
  {
    const float4* src = x + (size_t)b * 3 * 224 * 56;
    unsigned* dst = (unsigned*)lx;
#pragma unroll
    for (int it = 0; it < 6; ++it) {
      int i = it * 256 + tid;
      if (i < 1344) {
        int row = i / 56, d = i - row * 56;   // row = ic*8 + r
        int ic = row >> 3, r = row & 7;
        dst[i] = pack4(src[(ic * 224 + (oh0 + r)) * 56 + d], s_in);
      }
    }
  }
  __syncthreads();

  int mx = 0;
  for (int it = 0; it < 21; ++it) {
    int i = it * 256 + tid;
    int g = i % 28;
    int r = i / 28;
    int oh_l = r % 6;
    int oc = r / 6;

    int bias = lb[oc];
    int acc[8];
#pragma unroll
    for (int j = 0; j < 8; ++j) acc[j] = bias;

#pragma unroll
    for (int seg = 0; seg < 9; ++seg) {
      int ic = seg / 3, kh = seg - ic * 3;
      const signed char* base = lx + (ic * 8 + oh_l + kh) * 224 + g * 8;
      uint2 lo = *(const uint2*)base;
      unsigned d0 = lo.x, d1 = lo.y;
      unsigned d2 = *(const unsigned*)(base + 8);
      unsigned wr = lw[oc * 9 + ic * 3 + kh];
      acc[0] = dot4(d0, wr, acc[0]);
      acc[1] = dot4(alignb(d1, d0, 1), wr, acc[1]);
      acc[2] = dot4(alignb(d1, d0, 2), wr, acc[2]);
      acc[3] = dot4(alignb(d1, d0, 3), wr, acc[3]);
      acc[4] = dot4(d1, wr, acc[4]);
      acc[5] = dot4(alignb(d2, d1, 1), wr, acc[5]);
      acc[6] = dot4(alignb(d2, d1, 2), wr, acc[6]);
      acc[7] = dot4(alignb(d2, d1, 3), wr, acc[7]);
    }

#pragma unroll
    for (int j = 0; j < 8; ++j) if (g * 8 + j < 222) mx = max(mx, acc[j]);
  }
  mx = block_maxi(max(mx, 0));
  if (!tid) atomicMax(max1, mx);
}

// conv1 pass B: quantize-while-staging, recompute acc, quantize output in
// register, store NHWC uint8 codes coalesced (byte offset in 32B slot == oc).
__global__ void __launch_bounds__(256) k_conv1b(
    const float4* __restrict__ x, const float* __restrict__ w1,
    const float* __restrict__ b1, const Scal* __restrict__ sc,
    unsigned char* __restrict__ y1n) {
  __shared__ signed char lx[3 * 8 * 224 + 16];
  __shared__ unsigned lw[288];
  __shared__ int lb[32];
  int tid = threadIdx.x;
  int strip = blockIdx.x % 37;
  int b = blockIdx.x / 37;
  int oh0 = strip * 6;
  float s_in = d_s_in(sc), sw1 = d_sw1(sc);

  for (int i = tid; i < 288; i += 256) {
    int oc = i / 9, r = i - oc * 9;
    unsigned w = 0;
#pragma unroll
    for (int k = 0; k < 3; ++k) {
      float q = rintf(w1[oc * 27 + r * 3 + k] / sw1);
      q = fminf(fmaxf(q, -8.f), 7.f);
      w |= ((unsigned)((int)q & 255)) << (8 * k);
    }
    lw[i] = w;
  }
  if (tid < 32) lb[tid] = (int)rintf(b1[tid] / (s_in * sw1));
  {
    const float4* src = x + (size_t)b * 3 * 224 * 56;
    unsigned* dst = (unsigned*)lx;
#pragma unroll
    for (int it = 0; it < 6; ++it) {
      int i = it * 256 + tid;
      if (i < 1344) {
        int row = i / 56, d = i - row * 56;
        int ic = row >> 3, r = row & 7;
        dst[i] = pack4(src[(ic * 224 + (oh0 + r)) * 56 + d], s_in);
      }
    }
  }
  __syncthreads();

  float h1 = (s_in * sw1) / d_s1(sc);

  for (int it = 0; it < 21; ++it) {
    int t = it * 256 + tid;         // oc4 fast(8), g2(112), oh_l(6)
    int oc4 = t & 7;
    int r2 = t >> 3;
    int g2 = r2 % 112;
    int oh_l = r2 / 112;
    int p = g2 * 2;
    int qb = p & ~3, sh = p & 3;
    int oc0 = oc4 * 4;

    int acc0[4], acc1[4];
#pragma unroll
    for (int c = 0; c < 4; ++c) { acc0[c] = lb[oc0 + c]; acc1[c] = acc0[c]; }

#pragma unroll
    for (int seg = 0; seg < 9; ++seg) {
      int ic = seg / 3, kh = seg - ic * 3;
      const signed char* base = lx + (ic * 8 + oh_l + kh) * 224 + qb;
      unsigned d0 = *(const unsigned*)base;
      unsigned d1 = *(const unsigned*)(base + 4);
      unsigned wpx0 = alignb(d1, d0, sh);
      unsigned wpx1 = alignb(d1, d0, sh + 1);
#pragma unroll
      for (int c = 0; c < 4; ++c) {
        unsigned wr = lw[(oc0 + c) * 9 + seg];
        acc0[c] = dot4(wpx0, wr, acc0[c]);
        acc1[c] = dot4(wpx1, wr, acc1[c]);
      }
    }

    unsigned cw0 = 0, cw1 = 0;
#pragma unroll
    for (int c = 0; c < 4; ++c) {
      cw0 |= ((unsigned)(int)qclamp(acc0[c], h1)) << (8 * c);
      cw1 |= ((unsigned)(int)qclamp(acc1[c], h1)) << (8 * c);
    }
    size_t pidx = (size_t)(b * 222 + oh0 + oh_l) * 224 + p;
    unsigned* dst = (unsigned*)(y1n + pidx * 32 + oc0);
    dst[0] = cw0;
    dst[8] = cw1;
  }
}

// conv2 pass A: each wave owns ITER2 CONTIGUOUS tiles (32px x 2 rows x 64oc,
// 36 MFMA). Weights + per-block bint2 staged once; no barriers in loop.
__global__ void __launch_bounds__(256) k_conv2a(
    const unsigned char* __restrict__ y1n, const unsigned* __restrict__ w2frag,
    const float* __restrict__ b2, const Scal* __restrict__ sc, int* __restrict__ max2) {
  __shared__ unsigned lw[4608];
  __shared__ int lb2[64];
  int tid = threadIdx.x;
  for (int i = tid; i < 4608; i += 256) lw[i] = w2frag[i];
  if (tid < 64) {
    float sb = d_s1(sc) * d_sw2(sc);
    lb2[tid] = (int)rintf(b2[tid] / sb);
  }
  __syncthreads();

  int lane = tid & 63;
  int lane31 = lane & 31, lhalf = lane >> 5;
  int bias0 = lb2[lane31], bias1 = lb2[32 + lane31];
  size_t aoff = (size_t)lane31 * 32 + (size_t)lhalf * 16;
  int mx = 0;

  for (int it = 0; it < ITER2; ++it) {
    int tb = blockIdx.x * ITER2 + it;
    int wv = tb * 4 + (tid >> 6);
    int owg = wv % 7; int t = wv / 7;
    int ohg = t % 110; int b = t / 110;
    int oh0 = ohg * 2, ow0 = owg * 32;

    const unsigned char* base0 = y1n + ((size_t)((b * 222 + oh0) * 224 + ow0)) * 32 + aoff;
    v4i a[4][3];
#pragma unroll
    for (int i = 0; i < 4; ++i)
#pragma unroll
      for (int kw = 0; kw < 3; ++kw)
        a[i][kw] = *(const v4i*)(base0 + (size_t)i * (224 * 32) + kw * 32);

    v16i acc00, acc01, acc10, acc11;
#pragma unroll
    for (int r = 0; r < 16; ++r) {
      acc00[r] = bias0; acc01[r] = bias1;
      acc10[r] = bias0; acc11[r] = bias1;
    }

#pragma unroll
    for (int kh = 0; kh < 3; ++kh)
#pragma unroll
      for (int kw = 0; kw < 3; ++kw) {
        int tap = kh * 3 + kw;
        v4i b0 = *(const v4i*)(lw + (tap * 2 + 0) * 256 + lane * 4);
        v4i b1 = *(const v4i*)(lw + (tap * 2 + 1) * 256 + lane * 4);
        acc00 = __builtin_amdgcn_mfma_i32_32x32x32_i8(a[kh][kw], b0, acc00, 0, 0, 0);
        acc01 = __builtin_amdgcn_mfma_i32_32x32x32_i8(a[kh][kw], b1, acc01, 0, 0, 0);
        acc10 = __builtin_amdgcn_mfma_i32_32x32x32_i8(a[kh + 1][kw], b0, acc10, 0, 0, 0);
        acc11 = __builtin_amdgcn_mfma_i32_32x32x32_i8(a[kh + 1][kw], b1, acc11, 0, 0, 0);
      }

    if (owg != 6) {
#pragma unroll
      for (int r = 0; r < 16; ++r)
        mx = max(mx, max(max(acc00[r], acc01[r]), max(acc10[r], acc11[r])));
    } else {
#pragma unroll
      for (int r = 0; r < 16; ++r) {
        int m = (r & 3) + 8 * (r >> 2) + 4 * lhalf;
        if (ow0 + m < 220)
          mx = max(mx, max(max(acc00[r], acc01[r]), max(acc10[r], acc11[r])));
      }
    }
  }
  mx = block_maxi(max(mx, 0));
  if (!tid) atomicMax(max2, mx);
}

// conv2 pass B: recompute acc per tile, quantize in-register (float sums),
// pool into block-local ls[2048], flush at end.
__global__ void __launch_bounds__(256) k_conv2b(
    const unsigned char* __restrict__ y1n, const unsigned* __restrict__ w2frag,
    const float* __restrict__ b2, const Scal* __restrict__ sc,
    int* __restrict__ pooled_i) {
  __shared__ unsigned lw[4608];
  __shared__ int ls[2048];
  __shared__ int lb2[64];
  int tid = threadIdx.x;
  for (int i = tid; i < 4608; i += 256) lw[i] = w2frag[i];
  for (int i = tid; i < 2048; i += 256) ls[i] = 0;
  if (tid < 64) {
    float sb = d_s1(sc) * d_sw2(sc);
    lb2[tid] = (int)rintf(b2[tid] / sb);
  }
  __syncthreads();

  int lane = tid & 63;
  int lane31 = lane & 31, lhalf = lane >> 5;
  int bias0 = lb2[lane31], bias1 = lb2[32 + lane31];
  size_t aoff = (size_t)lane31 * 32 + (size_t)lhalf * 16;
  float h = (d_s1(sc) * d_sw2(sc)) * (1.0f / d_s2(sc));

  for (int it = 0; it < ITER2; ++it) {
    int tb = blockIdx.x * ITER2 + it;
    int wv = tb * 4 + (tid >> 6);
    int owg = wv % 7; int t = wv / 7;
    int ohg = t % 110; int b = t / 110;
    int oh0 = ohg * 2, ow0 = owg * 32;

    const unsigned char* base0 = y1n + ((size_t)((b * 222 + oh0) * 224 + ow0)) * 32 + aoff;
    v4i a[4][3];
#pragma unroll
    for (int i = 0; i < 4; ++i)
#pragma unroll
      for (int kw = 0; kw < 3; ++kw)
        a[i][kw] = *(const v4i*)(base0 + (size_t)i * (224 * 32) + kw * 32);

    v16i acc00, acc01, acc10, acc11;
#pragma unroll
    for (int r = 0; r < 16; ++r) {
      acc00[r] = bias0; acc01[r] = bias1;
      acc10[r] = bias0; acc11[r] = bias1;
    }

#pragma unroll
    for (int kh = 0; kh < 3; ++kh)
#pragma unroll
      for (int kw = 0; kw < 3; ++kw) {
        int tap = kh * 3 + kw;
        v4i b0 = *(const v4i*)(lw + (tap * 2 + 0) * 256 + lane * 4);
        v4i b1 = *(const v4i*)(lw + (tap * 2 + 1) * 256 + lane * 4);
        acc00 = __builtin_amdgcn_mfma_i32_32x32x32_i8(a[kh][kw], b0, acc00, 0, 0, 0);
        acc01 = __builtin_amdgcn_mfma_i32_32x32x32_i8(a[kh][kw], b1, acc01, 0, 0, 0);
        acc10 = __builtin_amdgcn_mfma_i32_32x32x32_i8(a[kh + 1][kw], b0, acc10, 0, 0, 0);
        acc11 = __builtin_amdgcn_mfma_i32_32x32x32_i8(a[kh + 1][kw], b1, acc11, 0, 0, 0);
      }

    float fs0 = 0.f, fs1 = 0.f;
    if (owg != 6) {
#pragma unroll
      for (int r = 0; r < 16; ++r) {
        fs0 += qclamp(acc00[r], h) + qclamp(acc10[r], h);
        fs1 += qclamp(acc01[r], h) + qclamp(acc11[r], h);
      }
    } else {
#pragma unroll
      for (int r = 0; r < 16; ++r) {
        int m = (r & 3) + 8 * (r >> 2) + 4 * lhalf;
        if (ow0 + m < 220) {
          fs0 += qclamp(acc00[r], h) + qclamp(acc10[r], h);
          fs1 += qclamp(acc01[r], h) + qclamp(acc11[r], h);
        }
      }
    }
    int isum0 = (int)fs0, isum1 = (int)fs1;
    isum0 += __shfl_down(isum0, 32, 64);
    isum1 += __shfl_down(isum1, 32, 64);
    if (lhalf == 0) {
      atomicAdd(&ls[b * 64 + lane31], isum0);
      atomicAdd(&ls[b * 64 + 32 + lane31], isum1);
    }
  }
  __syncthreads();
  for (int i = tid; i < 2048; i += 256) {
    int v = ls[i];
    if (v != 0) atomicAdd(&pooled_i[i], v);
  }
}

// whole FC head + log_softmax in one 1024-thread block.
__global__ void __launch_bounds__(1024) k_fc(
    const int* __restrict__ pooled_i, const float* __restrict__ wf1,
    const float* __restrict__ bf1, const float* __restrict__ wf2,
    const float* __restrict__ bf2, const Scal* __restrict__ sc,
    float* __restrict__ out) {
  __shared__ float pl[2048];
  __shared__ float wq1[128 * 65];
  __shared__ float y3[32 * 130];
  __shared__ float zz[320];
  __shared__ float s3sh;
  __shared__ float red16[16];
  int tid = threadIdx.x;
  float swf1 = mkscale(sc->max_wf1, 7.f), swf2 = mkscale(sc->max_wf2, 7.f);
  float s2 = d_s2(sc);
  for (int i = tid; i < 2048; i += 1024) pl[i] = (float)pooled_i[i] * s2 / 48400.0f;
  for (int i = tid; i < 8192; i += 1024) {
    float q = rintf(wf1[i] / swf1);
    q = fminf(fmaxf(q, -8.f), 7.f);
    wq1[(i >> 6) * 65 + (i & 63)] = q * swf1;
  }
  __syncthreads();
  float sb1 = s2 * swf1;
  float lmax = 0.f;
#pragma unroll
  for (int o = tid; o < 4096; o += 1024) {
    int b = o >> 7, j = o & 127;
    float acc = rintf(bf1[j] / sb1) * sb1;
    const float* wrow = &wq1[j * 65];
    const float* xrow = &pl[b * 64];
#pragma unroll 16
    for (int k = 0; k < 64; ++k) acc += xrow[k] * wrow[k];
    float r = fmaxf(acc, 0.f);
    y3[b * 130 + j] = r;
    lmax = fmaxf(lmax, r);
  }
  lmax = wave_maxf(lmax);
  {
    int lane = tid & 63, w = tid >> 6;
    if (!lane) red16[w] = lmax;
  }
  __syncthreads();
  if (tid < 64) {
    float t = (tid < 16) ? red16[tid] : 0.f;
    t = wave_maxf(t);
    if (!tid) s3sh = fmaxf(t, 1e-8f) / 15.f;
  }
  __syncthreads();
  float s3 = s3sh;
  float sb2 = s3 * swf2;
  if (tid < 320) {
    int o = tid;
    int b = o / 10, j = o - b * 10;
    float acc = rintf(bf2[j] / sb2) * sb2;
    const float* yy = &y3[b * 130];
    const float* wrow = &wf2[j * 128];
#pragma unroll 16
    for (int k = 0; k < 128; ++k) {
      float q = rintf(yy[k] / s3);
      q = fminf(fmaxf(q, 0.f), 15.f);
      float wv = rintf(wrow[k] / swf2);
      wv = fminf(fmaxf(wv, -8.f), 7.f);
      acc += (q * s3) * (wv * swf2);
    }
    zz[o] = acc;
  }
  __syncthreads();
  if (tid < 32) {
    const float* z = &zz[tid * 10];
    float mm = z[0];
    for (int k = 1; k < 10; ++k) mm = fmaxf(mm, z[k]);
    float ssum = 0.f;
    for (int k = 0; k < 10; ++k) ssum += expf(z[k] - mm);
    float l = mm + logf(ssum);
    for (int k = 0; k < 10; ++k) out[tid * 10 + k] = z[k] - l;
  }
}

extern "C" void kernel_launch(void* const* d_in, const int* in_sizes, int n_in,
                              void* d_out, int out_size, void* d_ws, size_t ws_size,
                              hipStream_t stream) {
  const float* x   = (const float*)d_in[0];
  const float* w1  = (const float*)d_in[1];
  const float* b1  = (const float*)d_in[2];
  const float* w2  = (const float*)d_in[3];
  const float* b2  = (const float*)d_in[4];
  const float* wf1 = (const float*)d_in[5];
  const float* bf1 = (const float*)d_in[6];
  const float* wf2 = (const float*)d_in[7];
  const float* bf2 = (const float*)d_in[8];
  float* out = (float*)d_out;

  char* ws = (char*)d_ws;
  Scal* sc = (Scal*)ws;
  int* pooled_i = (int*)(ws + 1024);            // sc + pooled zeroed by ONE memset
  size_t off = 1024 + 8192;
  unsigned* w2frag = (unsigned*)(ws + off);     off += 4608 * 4;          // MFMA B-frag layout
  off = (off + 255) & ~(size_t)255;
  unsigned char* y1n = (unsigned char*)(ws + off); off += (size_t)NP1 + 256; // NHWC codes + slack
  (void)ws_size; (void)in_sizes; (void)n_in; (void)out_size;

  hipMemsetAsync(ws, 0, 1024 + 8192, stream);
  k_absmax_xw<<<1028, 256, 0, stream>>>((const float4*)x, NX / 4, w1, w2, wf1, wf2, sc);
  k_conv1a<<<1184 + 18, 256, 0, stream>>>((const float4*)x, w1, b1, w2, sc, w2frag, &sc->max1);
  k_conv1b<<<1184, 256, 0, stream>>>((const float4*)x, w1, b1, sc, y1n);
  k_conv2a<<<NBLK2, 256, 0, stream>>>(y1n, w2frag, b2, sc, &sc->max2);
  k_conv2b<<<NBLK2, 256, 0, stream>>>(y1n, w2frag, b2, sc, pooled_i);
  k_fc<<<1, 1024, 0, stream>>>(pooled_i, wf1, bf1, wf2, bf2, sc, out);
}

// Round 23
// 287.348 us; speedup vs baseline: 2.6460x; 1.0065x over previous
//
#include <hip/hip_runtime.h>
#include <cstdint>
#include <cstddef>

#define DI __device__ __forceinline__

typedef int v4i  __attribute__((ext_vector_type(4)));
typedef int v16i __attribute__((ext_vector_type(16)));

#if defined(__has_builtin)
#if __has_builtin(__builtin_amdgcn_sdot4)
#define HAS_SDOT4 1
#endif
#if __has_builtin(__builtin_amdgcn_alignbyte)
#define HAS_ALIGNBYTE 1
#endif
#endif

DI int dot4(unsigned a, unsigned b, int c) {
#ifdef HAS_SDOT4
  return __builtin_amdgcn_sdot4((int)a, (int)b, c, false);
#else
#pragma unroll
  for (int k = 0; k < 4; ++k)
    c += (int)(signed char)(a >> (8 * k)) * (int)(signed char)(b >> (8 * k));
  return c;
#endif
}

DI unsigned alignb(unsigned hi, unsigned lo, int sh) {  // bytes (hi:lo) >> 8*sh
#ifdef HAS_ALIGNBYTE
  return __builtin_amdgcn_alignbyte(hi, lo, sh);
#else
  return sh ? ((lo >> (8 * sh)) | (hi << (32 - 8 * sh))) : lo;
#endif
}

DI float qclamp(int a, float h) {  // clamp(rint(a*h), 0, 15) as float
  return fminf(fmaxf(rintf((float)a * h), 0.f), 15.f);
}

DI unsigned pack4(float4 v, float s) {  // quantize 4 floats -> 4 int8 codes
  float f[4] = {v.x, v.y, v.z, v.w};
  unsigned w = 0;
#pragma unroll
  for (int k = 0; k < 4; ++k) {
    float q = rintf(f[k] / s);
    q = fminf(fmaxf(q, -8.f), 7.f);
    w |= ((unsigned)((int)q & 255)) << (8 * k);
  }
  return w;
}

// ---------------- scalar block in workspace ----------------
struct Scal {
  unsigned max_x, max_w1, max_w2, max_wf1, max_wf2;  // float bits (abs-max, >=0)
  int max1, max2;
};

DI float mkscale(unsigned bits, float d) { return fmaxf(__uint_as_float(bits), 1e-8f) / d; }
DI float d_s_in(const Scal* sc) { return mkscale(sc->max_x, 7.f); }
DI float d_sw1(const Scal* sc)  { return mkscale(sc->max_w1, 7.f); }
DI float d_sw2(const Scal* sc)  { return mkscale(sc->max_w2, 7.f); }
DI float d_s1(const Scal* sc)   { return fmaxf((float)sc->max1 * (d_s_in(sc) * d_sw1(sc)), 1e-8f) / 15.f; }
DI float d_s2(const Scal* sc)   { return fmaxf((float)sc->max2 * (d_s1(sc) * d_sw2(sc)), 1e-8f) / 15.f; }

static constexpr int NX   = 32 * 3 * 224 * 224;     // 4,816,896
static constexpr int NP1  = 32 * 32 * 222 * 224;    // y1n bytes (padded NHWC codes)
static constexpr int NBLK2 = 1540;                  // conv2 blocks (6.01/CU)
static constexpr int ITER2 = 4;                     // contiguous tiles per wave (6160 total)
static constexpr int WPB2 = 770;                    // conv2 waves per batch image

// ---------------- reduction helpers (blockDim == 256) ----------------
DI float wave_maxf(float v) { for (int o = 32; o; o >>= 1) v = fmaxf(v, __shfl_down(v, o, 64)); return v; }
DI int   wave_maxi(int v)   { for (int o = 32; o; o >>= 1) v = max(v, __shfl_down(v, o, 64));   return v; }

DI float block_maxf(float v) {
  __shared__ float s[4];
  v = wave_maxf(v);
  int lane = threadIdx.x & 63, w = threadIdx.x >> 6;
  if (!lane) s[w] = v;
  __syncthreads();
  if (threadIdx.x < 64) {
    float t = (threadIdx.x < 4) ? s[threadIdx.x] : 0.f;
    v = wave_maxf(t);
  }
  return v;
}

DI int block_maxi(int v) {
  __shared__ int s[4];
  v = wave_maxi(v);
  int lane = threadIdx.x & 63, w = threadIdx.x >> 6;
  if (!lane) s[w] = v;
  __syncthreads();
  if (threadIdx.x < 64) {
    int t = (threadIdx.x < 4) ? s[threadIdx.x] : 0;
    v = wave_maxi(t);
  }
  return v;
}

// ---------------- stage kernels ----------------
// merged absmax: blocks 0..1023 = x (grid-stride); 1024..1027 = weights
__global__ void k_absmax_xw(const float4* __restrict__ x, int n4,
                            const float* __restrict__ w1, const float* __restrict__ w2,
                            const float* __restrict__ wf1, const float* __restrict__ wf2,
                            Scal* sc) {
  if (blockIdx.x < 1024) {
    float m = 0.f;
    for (int i = blockIdx.x * 256 + threadIdx.x; i < n4; i += 1024 * 256) {
      float4 v = x[i];
      m = fmaxf(m, fmaxf(fmaxf(fabsf(v.x), fabsf(v.y)), fmaxf(fabsf(v.z), fabsf(v.w))));
    }
    m = block_maxf(m);
    if (!threadIdx.x) atomicMax(&sc->max_x, __float_as_uint(m));
    return;
  }
  const float* p; int n; unsigned* slot;
  int wb = blockIdx.x - 1024;
  if (wb == 0)      { p = w1;  n = 864;   slot = &sc->max_w1; }
  else if (wb == 1) { p = w2;  n = 18432; slot = &sc->max_w2; }
  else if (wb == 2) { p = wf1; n = 8192;  slot = &sc->max_wf1; }
  else              { p = wf2; n = 1280;  slot = &sc->max_wf2; }
  float m = 0.f;
  for (int i = threadIdx.x; i < n; i += 256) m = fmaxf(m, fabsf(p[i]));
  m = block_maxf(m);
  if (!threadIdx.x) atomicMax(slot, __float_as_uint(m));
}

// conv1 pass A: quantize-while-staging (x floats -> LDS codes), per-block
// w1/bias packing from raw inputs, MAX ONLY. Blocks >= 1184 pack w2frag.
__global__ void __launch_bounds__(256) k_conv1a(
    const float4* __restrict__ x, const float* __restrict__ w1,
    const float* __restrict__ b1, const float* __restrict__ w2,
    const Scal* __restrict__ sc, unsigned* __restrict__ w2frag,
    int* __restrict__ max1) {
  int tid = threadIdx.x;
  if (blockIdx.x >= 1184) {   // 18 blocks: pack w2 into MFMA B-frag layout
    int j = (blockIdx.x - 1184) * 256 + tid;   // 0..4607
    int icq = j & 7; int t = j >> 3;
    int kw = t % 3; t /= 3;
    int kh = t % 3; int oc = t / 3;
    float s = d_sw2(sc);
    unsigned w = 0;
#pragma unroll
    for (int k = 0; k < 4; ++k) {
      int ic = icq * 4 + k;
      float q = rintf(w2[(oc * 32 + ic) * 9 + kh * 3 + kw] / s);
      q = fminf(fmaxf(q, -8.f), 7.f);
      w |= ((unsigned)((int)q & 255)) << (8 * k);
    }
    int tap = kh * 3 + kw;
    int dl = (oc & 31) | ((icq >> 2) << 5);
    w2frag[(((tap * 2) + (oc >> 5)) * 64 + dl) * 4 + (icq & 3)] = w;
    return;
  }

  __shared__ signed char lx[3 * 8 * 224 + 16];
  __shared__ unsigned lw[288];
  __shared__ int lb[32];
  int strip = blockIdx.x % 37;   // 0..36
  int b = blockIdx.x / 37;       // 0..31
  int oh0 = strip * 6;
  float s_in = d_s_in(sc), sw1 = d_sw1(sc);

  for (int i = tid; i < 288; i += 256) {
    int oc = i / 9, r = i - oc * 9;
    unsigned w = 0;
#pragma unroll
    for (int k = 0; k < 3; ++k) {
      float q = rintf(w1[oc * 27 + r * 3 + k] / sw1);
      q = fminf(fmaxf(q, -8.f), 7.f);
      w |= ((unsigned)((int)q & 255)) << (8 * k);
    }
    lw[i] = w;
  }
  if (tid < 32) lb[tid] = (int)rintf(b1[tid] / (s_in * sw1));
  {
    const float4* src = x + (size_t)b * 3 * 224 * 56;
    unsigned* dst = (unsigned*)lx;
#pragma unroll
    for (int it = 0; it < 6; ++it) {
      int i = it * 256 + tid;
      if (i < 1344) {
        int row = i / 56, d = i - row * 56;   // row = ic*8 + r
        int ic = row >> 3, r = row & 7;
        dst[i] = pack4(src[(ic * 224 + (oh0 + r)) * 56 + d], s_in);
      }
    }
  }
  __syncthreads();

  int mx = 0;
  for (int it = 0; it < 21; ++it) {
    int i = it * 256 + tid;
    int g = i % 28;
    int r = i / 28;
    int oh_l = r % 6;
    int oc = r / 6;

    int bias = lb[oc];
    int acc[8];
#pragma unroll
    for (int j = 0; j < 8; ++j) acc[j] = bias;

#pragma unroll
    for (int seg = 0; seg < 9; ++seg) {
      int ic = seg / 3, kh = seg - ic * 3;
      const signed char* base = lx + (ic * 8 + oh_l + kh) * 224 + g * 8;
      uint2 lo = *(const uint2*)base;
      unsigned d0 = lo.x, d1 = lo.y;
      unsigned d2 = *(const unsigned*)(base + 8);
      unsigned wr = lw[oc * 9 + ic * 3 + kh];
      acc[0] = dot4(d0, wr, acc[0]);
      acc[1] = dot4(alignb(d1, d0, 1), wr, acc[1]);
      acc[2] = dot4(alignb(d1, d0, 2), wr, acc[2]);
      acc[3] = dot4(alignb(d1, d0, 3), wr, acc[3]);
      acc[4] = dot4(d1, wr, acc[4]);
      acc[5] = dot4(alignb(d2, d1, 1), wr, acc[5]);
      acc[6] = dot4(alignb(d2, d1, 2), wr, acc[6]);
      acc[7] = dot4(alignb(d2, d1, 3), wr, acc[7]);
    }

#pragma unroll
    for (int j = 0; j < 8; ++j) if (g * 8 + j < 222) mx = max(mx, acc[j]);
  }
  mx = block_maxi(max(mx, 0));
  if (!tid) atomicMax(max1, mx);
}

// conv1 pass B: quantize-while-staging, recompute acc, quantize output in
// register, store NHWC uint8 codes coalesced (byte offset in 32B slot == oc).
__global__ void __launch_bounds__(256) k_conv1b(
    const float4* __restrict__ x, const float* __restrict__ w1,
    const float* __restrict__ b1, const Scal* __restrict__ sc,
    unsigned char* __restrict__ y1n) {
  __shared__ signed char lx[3 * 8 * 224 + 16];
  __shared__ unsigned lw[288];
  __shared__ int lb[32];
  int tid = threadIdx.x;
  int strip = blockIdx.x % 37;
  int b = blockIdx.x / 37;
  int oh0 = strip * 6;
  float s_in = d_s_in(sc), sw1 = d_sw1(sc);

  for (int i = tid; i < 288; i += 256) {
    int oc = i / 9, r = i - oc * 9;
    unsigned w = 0;
#pragma unroll
    for (int k = 0; k < 3; ++k) {
      float q = rintf(w1[oc * 27 + r * 3 + k] / sw1);
      q = fminf(fmaxf(q, -8.f), 7.f);
      w |= ((unsigned)((int)q & 255)) << (8 * k);
    }
    lw[i] = w;
  }
  if (tid < 32) lb[tid] = (int)rintf(b1[tid] / (s_in * sw1));
  {
    const float4* src = x + (size_t)b * 3 * 224 * 56;
    unsigned* dst = (unsigned*)lx;
#pragma unroll
    for (int it = 0; it < 6; ++it) {
      int i = it * 256 + tid;
      if (i < 1344) {
        int row = i / 56, d = i - row * 56;
        int ic = row >> 3, r = row & 7;
        dst[i] = pack4(src[(ic * 224 + (oh0 + r)) * 56 + d], s_in);
      }
    }
  }
  __syncthreads();

  float h1 = (s_in * sw1) / d_s1(sc);

  for (int it = 0; it < 21; ++it) {
    int t = it * 256 + tid;         // oc4 fast(8), g2(112), oh_l(6)
    int oc4 = t & 7;
    int r2 = t >> 3;
    int g2 = r2 % 112;
    int oh_l = r2 / 112;
    int p = g2 * 2;
    int qb = p & ~3, sh = p & 3;
    int oc0 = oc4 * 4;

    int acc0[4], acc1[4];
#pragma unroll
    for (int c = 0; c < 4; ++c) { acc0[c] = lb[oc0 + c]; acc1[c] = acc0[c]; }

#pragma unroll
    for (int seg = 0; seg < 9; ++seg) {
      int ic = seg / 3, kh = seg - ic * 3;
      const signed char* base = lx + (ic * 8 + oh_l + kh) * 224 + qb;
      unsigned d0 = *(const unsigned*)base;
      unsigned d1 = *(const unsigned*)(base + 4);
      unsigned wpx0 = alignb(d1, d0, sh);
      unsigned wpx1 = alignb(d1, d0, sh + 1);
#pragma unroll
      for (int c = 0; c < 4; ++c) {
        unsigned wr = lw[(oc0 + c) * 9 + seg];
        acc0[c] = dot4(wpx0, wr, acc0[c]);
        acc1[c] = dot4(wpx1, wr, acc1[c]);
      }
    }

    unsigned cw0 = 0, cw1 = 0;
#pragma unroll
    for (int c = 0; c < 4; ++c) {
      cw0 |= ((unsigned)(int)qclamp(acc0[c], h1)) << (8 * c);
      cw1 |= ((unsigned)(int)qclamp(acc1[c], h1)) << (8 * c);
    }
    size_t pidx = (size_t)(b * 222 + oh0 + oh_l) * 224 + p;
    unsigned* dst = (unsigned*)(y1n + pidx * 32 + oc0);
    dst[0] = cw0;
    dst[8] = cw1;
  }
}

// conv2 pass A: each wave owns ITER2 CONTIGUOUS tiles (32px x 2 rows x 64oc,
// 36 MFMA). Weights + per-block bint2 staged once; no barriers in loop.
__global__ void __launch_bounds__(256) k_conv2a(
    const unsigned char* __restrict__ y1n, const unsigned* __restrict__ w2frag,
    const float* __restrict__ b2, const Scal* __restrict__ sc, int* __restrict__ max2) {
  __shared__ unsigned lw[4608];
  __shared__ int lb2[64];
  int tid = threadIdx.x;
  for (int i = tid; i < 4608; i += 256) lw[i] = w2frag[i];
  if (tid < 64) {
    float sb = d_s1(sc) * d_sw2(sc);
    lb2[tid] = (int)rintf(b2[tid] / sb);
  }
  __syncthreads();

  int lane = tid & 63;
  int lane31 = lane & 31, lhalf = lane >> 5;
  int bias0 = lb2[lane31], bias1 = lb2[32 + lane31];
  size_t aoff = (size_t)lane31 * 32 + (size_t)lhalf * 16;
  int mx = 0;

  for (int it = 0; it < ITER2; ++it) {
    int tb = blockIdx.x * ITER2 + it;
    int wv = tb * 4 + (tid >> 6);
    int owg = wv % 7; int t = wv / 7;
    int ohg = t % 110; int b = t / 110;
    int oh0 = ohg * 2, ow0 = owg * 32;

    const unsigned char* base0 = y1n + ((size_t)((b * 222 + oh0) * 224 + ow0)) * 32 + aoff;
    v4i a[4][3];
#pragma unroll
    for (int i = 0; i < 4; ++i)
#pragma unroll
      for (int kw = 0; kw < 3; ++kw)
        a[i][kw] = *(const v4i*)(base0 + (size_t)i * (224 * 32) + kw * 32);

    v16i acc00, acc01, acc10, acc11;
#pragma unroll
    for (int r = 0; r < 16; ++r) {
      acc00[r] = bias0; acc01[r] = bias1;
      acc10[r] = bias0; acc11[r] = bias1;
    }

#pragma unroll
    for (int kh = 0; kh < 3; ++kh)
#pragma unroll
      for (int kw = 0; kw < 3; ++kw) {
        int tap = kh * 3 + kw;
        v4i b0 = *(const v4i*)(lw + (tap * 2 + 0) * 256 + lane * 4);
        v4i b1 = *(const v4i*)(lw + (tap * 2 + 1) * 256 + lane * 4);
        acc00 = __builtin_amdgcn_mfma_i32_32x32x32_i8(a[kh][kw], b0, acc00, 0, 0, 0);
        acc01 = __builtin_amdgcn_mfma_i32_32x32x32_i8(a[kh][kw], b1, acc01, 0, 0, 0);
        acc10 = __builtin_amdgcn_mfma_i32_32x32x32_i8(a[kh + 1][kw], b0, acc10, 0, 0, 0);
        acc11 = __builtin_amdgcn_mfma_i32_32x32x32_i8(a[kh + 1][kw], b1, acc11, 0, 0, 0);
      }

    if (owg != 6) {
#pragma unroll
      for (int r = 0; r < 16; ++r)
        mx = max(mx, max(max(acc00[r], acc01[r]), max(acc10[r], acc11[r])));
    } else {
#pragma unroll
      for (int r = 0; r < 16; ++r) {
        int m = (r & 3) + 8 * (r >> 2) + 4 * lhalf;
        if (ow0 + m < 220)
          mx = max(mx, max(max(acc00[r], acc01[r]), max(acc10[r], acc11[r])));
      }
    }
  }
  mx = block_maxi(max(mx, 0));
  if (!tid) atomicMax(max2, mx);
}

// conv2 pass B: recompute acc per tile, quantize in-register (float sums),
// pool into 2-slot LDS accumulator (block spans <=2 batch images), flush once.
__global__ void __launch_bounds__(256) k_conv2b(
    const unsigned char* __restrict__ y1n, const unsigned* __restrict__ w2frag,
    const float* __restrict__ b2, const Scal* __restrict__ sc,
    int* __restrict__ pooled_i) {
  __shared__ unsigned lw[4608];
  __shared__ int ls[128];
  __shared__ int lb2[64];
  int tid = threadIdx.x;
  for (int i = tid; i < 4608; i += 256) lw[i] = w2frag[i];
  if (tid < 128) ls[tid] = 0;
  if (tid < 64) {
    float sb = d_s1(sc) * d_sw2(sc);
    lb2[tid] = (int)rintf(b2[tid] / sb);
  }
  __syncthreads();

  int lane = tid & 63;
  int lane31 = lane & 31, lhalf = lane >> 5;
  int bias0 = lb2[lane31], bias1 = lb2[32 + lane31];
  size_t aoff = (size_t)lane31 * 32 + (size_t)lhalf * 16;
  float h = (d_s1(sc) * d_sw2(sc)) * (1.0f / d_s2(sc));
  int b_first = (blockIdx.x * ITER2 * 4) / WPB2;

  for (int it = 0; it < ITER2; ++it) {
    int tb = blockIdx.x * ITER2 + it;
    int wv = tb * 4 + (tid >> 6);
    int owg = wv % 7; int t = wv / 7;
    int ohg = t % 110; int b = t / 110;
    int oh0 = ohg * 2, ow0 = owg * 32;
    int slot = b - b_first;  // 0 or 1 (16 consecutive waves span <=2 images)

    const unsigned char* base0 = y1n + ((size_t)((b * 222 + oh0) * 224 + ow0)) * 32 + aoff;
    v4i a[4][3];
#pragma unroll
    for (int i = 0; i < 4; ++i)
#pragma unroll
      for (int kw = 0; kw < 3; ++kw)
        a[i][kw] = *(const v4i*)(base0 + (size_t)i * (224 * 32) + kw * 32);

    v16i acc00, acc01, acc10, acc11;
#pragma unroll
    for (int r = 0; r < 16; ++r) {
      acc00[r] = bias0; acc01[r] = bias1;
      acc10[r] = bias0; acc11[r] = bias1;
    }

#pragma unroll
    for (int kh = 0; kh < 3; ++kh)
#pragma unroll
      for (int kw = 0; kw < 3; ++kw) {
        int tap = kh * 3 + kw;
        v4i b0 = *(const v4i*)(lw + (tap * 2 + 0) * 256 + lane * 4);
        v4i b1 = *(const v4i*)(lw + (tap * 2 + 1) * 256 + lane * 4);
        acc00 = __builtin_amdgcn_mfma_i32_32x32x32_i8(a[kh][kw], b0, acc00, 0, 0, 0);
        acc01 = __builtin_amdgcn_mfma_i32_32x32x32_i8(a[kh][kw], b1, acc01, 0, 0, 0);
        acc10 = __builtin_amdgcn_mfma_i32_32x32x32_i8(a[kh + 1][kw], b0, acc10, 0, 0, 0);
        acc11 = __builtin_amdgcn_mfma_i32_32x32x32_i8(a[kh + 1][kw], b1, acc11, 0, 0, 0);
      }

    float fs0 = 0.f, fs1 = 0.f;
    if (owg != 6) {
#pragma unroll
      for (int r = 0; r < 16; ++r) {
        fs0 += qclamp(acc00[r], h) + qclamp(acc10[r], h);
        fs1 += qclamp(acc01[r], h) + qclamp(acc11[r], h);
      }
    } else {
#pragma unroll
      for (int r = 0; r < 16; ++r) {
        int m = (r & 3) + 8 * (r >> 2) + 4 * lhalf;
        if (ow0 + m < 220) {
          fs0 += qclamp(acc00[r], h) + qclamp(acc10[r], h);
          fs1 += qclamp(acc01[r], h) + qclamp(acc11[r], h);
        }
      }
    }
    int isum0 = (int)fs0, isum1 = (int)fs1;
    isum0 += __shfl_down(isum0, 32, 64);
    isum1 += __shfl_down(isum1, 32, 64);
    if (lhalf == 0) {
      atomicAdd(&ls[slot * 64 + lane31], isum0);
      atomicAdd(&ls[slot * 64 + 32 + lane31], isum1);
    }
  }
  __syncthreads();
  if (tid < 128) {
    int bb = b_first + (tid >> 6);
    int v = ls[tid];
    if (bb < 32 && v != 0) atomicAdd(&pooled_i[bb * 64 + (tid & 63)], v);
  }
}

// whole FC head + log_softmax in one 1024-thread block.
__global__ void __launch_bounds__(1024) k_fc(
    const int* __restrict__ pooled_i, const float* __restrict__ wf1,
    const float* __restrict__ bf1, const float* __restrict__ wf2,
    const float* __restrict__ bf2, const Scal* __restrict__ sc,
    float* __restrict__ out) {
  __shared__ float pl[2048];
  __shared__ float wq1[128 * 65];
  __shared__ float y3[32 * 130];
  __shared__ float zz[320];
  __shared__ float s3sh;
  __shared__ float red16[16];
  int tid = threadIdx.x;
  float swf1 = mkscale(sc->max_wf1, 7.f), swf2 = mkscale(sc->max_wf2, 7.f);
  float s2 = d_s2(sc);
  for (int i = tid; i < 2048; i += 1024) pl[i] = (float)pooled_i[i] * s2 / 48400.0f;
  for (int i = tid; i < 8192; i += 1024) {
    float q = rintf(wf1[i] / swf1);
    q = fminf(fmaxf(q, -8.f), 7.f);
    wq1[(i >> 6) * 65 + (i & 63)] = q * swf1;
  }
  __syncthreads();
  float sb1 = s2 * swf1;
  float lmax = 0.f;
#pragma unroll
  for (int o = tid; o < 4096; o += 1024) {
    int b = o >> 7, j = o & 127;
    float acc = rintf(bf1[j] / sb1) * sb1;
    const float* wrow = &wq1[j * 65];
    const float* xrow = &pl[b * 64];
#pragma unroll 16
    for (int k = 0; k < 64; ++k) acc += xrow[k] * wrow[k];
    float r = fmaxf(acc, 0.f);
    y3[b * 130 + j] = r;
    lmax = fmaxf(lmax, r);
  }
  lmax = wave_maxf(lmax);
  {
    int lane = tid & 63, w = tid >> 6;
    if (!lane) red16[w] = lmax;
  }
  __syncthreads();
  if (tid < 64) {
    float t = (tid < 16) ? red16[tid] : 0.f;
    t = wave_maxf(t);
    if (!tid) s3sh = fmaxf(t, 1e-8f) / 15.f;
  }
  __syncthreads();
  float s3 = s3sh;
  float sb2 = s3 * swf2;
  if (tid < 320) {
    int o = tid;
    int b = o / 10, j = o - b * 10;
    float acc = rintf(bf2[j] / sb2) * sb2;
    const float* yy = &y3[b * 130];
    const float* wrow = &wf2[j * 128];
#pragma unroll 16
    for (int k = 0; k < 128; ++k) {
      float q = rintf(yy[k] / s3);
      q = fminf(fmaxf(q, 0.f), 15.f);
      float wv = rintf(wrow[k] / swf2);
      wv = fminf(fmaxf(wv, -8.f), 7.f);
      acc += (q * s3) * (wv * swf2);
    }
    zz[o] = acc;
  }
  __syncthreads();
  if (tid < 32) {
    const float* z = &zz[tid * 10];
    float mm = z[0];
    for (int k = 1; k < 10; ++k) mm = fmaxf(mm, z[k]);
    float ssum = 0.f;
    for (int k = 0; k < 10; ++k) ssum += expf(z[k] - mm);
    float l = mm + logf(ssum);
    for (int k = 0; k < 10; ++k) out[tid * 10 + k] = z[k] - l;
  }
}

extern "C" void kernel_launch(void* const* d_in, const int* in_sizes, int n_in,
                              void* d_out, int out_size, void* d_ws, size_t ws_size,
                              hipStream_t stream) {
  const float* x   = (const float*)d_in[0];
  const float* w1  = (const float*)d_in[1];
  const float* b1  = (const float*)d_in[2];
  const float* w2  = (const float*)d_in[3];
  const float* b2  = (const float*)d_in[4];
  const float* wf1 = (const float*)d_in[5];
  const float* bf1 = (const float*)d_in[6];
  const float* wf2 = (const float*)d_in[7];
  const float* bf2 = (const float*)d_in[8];
  float* out = (float*)d_out;

  char* ws = (char*)d_ws;
  Scal* sc = (Scal*)ws;
  int* pooled_i = (int*)(ws + 1024);            // sc + pooled zeroed by ONE memset
  size_t off = 1024 + 8192;
  unsigned* w2frag = (unsigned*)(ws + off);     off += 4608 * 4;          // MFMA B-frag layout
  off = (off + 255) & ~(size_t)255;
  unsigned char* y1n = (unsigned char*)(ws + off); off += (size_t)NP1 + 256; // NHWC codes + slack
  (void)ws_size; (void)in_sizes; (void)n_in; (void)out_size;

  hipMemsetAsync(ws, 0, 1024 + 8192, stream);
  k_absmax_xw<<<1028, 256, 0, stream>>>((const float4*)x, NX / 4, w1, w2, wf1, wf2, sc);
  k_conv1a<<<1184 + 18, 256, 0, stream>>>((const float4*)x, w1, b1, w2, sc, w2frag, &sc->max1);
  k_conv1b<<<1184, 256, 0, stream>>>((const float4*)x, w1, b1, sc, y1n);
  k_conv2a<<<NBLK2, 256, 0, stream>>>(y1n, w2frag, b2, sc, &sc->max2);
  k_conv2b<<<NBLK2, 256, 0, stream>>>(y1n, w2frag, b2, sc, pooled_i);
  k_fc<<<1, 1024, 0, stream>>>(pooled_i, wf1, bf1, wf2, bf2, sc, out);
}